// Round 1
// baseline (1844.031 us; speedup 1.0000x reference)
//
#include <hip/hip_runtime.h>
#include <hip/hip_bf16.h>

// Problem constants (from reference)
constexpr int N1_SRC = 1171456;
constexpr int N1_TGT = 45056;
constexpr int N2_TGT = 4096;
constexpr int E1 = 1126400;
constexpr int E2 = 40960;
constexpr int IN_C = 128;
constexpr int HID_C = 256;
constexpr int OUT_C = 64;

// Workspace layout (floats)
constexpr size_t OFF_SUM1 = 0;                                   // 45056*128
constexpr size_t OFF_CNT1 = OFF_SUM1 + (size_t)N1_TGT * IN_C;    // 45056
constexpr size_t OFF_SUM2 = OFF_CNT1 + N1_TGT;                   // 4096*256
constexpr size_t OFF_CNT2 = OFF_SUM2 + (size_t)N2_TGT * HID_C;   // 4096
constexpr size_t OFF_H    = OFF_CNT2 + N2_TGT;                   // 45056*256
constexpr size_t OFF_LOG  = OFF_H + (size_t)N1_TGT * HID_C;      // 4096*64
constexpr size_t ZERO_FLOATS = OFF_H;                            // zero sum/cnt regions

// ---------------------------------------------------------------------------
// Kernel 1: layer-1 edge scatter. One wave per edge; lane handles 2 channels.
__global__ __launch_bounds__(256) void scatter1(
    const float* __restrict__ x, const int* __restrict__ src,
    const int* __restrict__ dst, float* __restrict__ sum1,
    float* __restrict__ cnt1) {
  const int lane = threadIdx.x & 63;
  const int wave = (blockIdx.x * blockDim.x + threadIdx.x) >> 6;
  const int nwaves = (gridDim.x * blockDim.x) >> 6;
  for (int e = wave; e < E1; e += nwaves) {
    const int s = src[e];
    const int d = dst[e];
    const float2 v =
        *reinterpret_cast<const float2*>(x + (size_t)s * IN_C + lane * 2);
    float* o = sum1 + (size_t)d * IN_C + lane * 2;
    unsafeAtomicAdd(o + 0, v.x);
    unsafeAtomicAdd(o + 1, v.y);
    if (lane == 0) unsafeAtomicAdd(cnt1 + d, 1.0f);
  }
}

// ---------------------------------------------------------------------------
// Kernel 2: h = relu(agg1 @ Wl1 + x[:N1_TGT] @ Wr1 + b1)
// Tiled fp32 GEMM: BM=64 x BN=64, 256 threads, 4x4 per thread, K staged in LDS.
constexpr int BM = 64, BN = 64, BK = 16;
__global__ __launch_bounds__(256) void l1_dense(
    const float* __restrict__ sum1, const float* __restrict__ cnt1,
    const float* __restrict__ x, const float* __restrict__ Wl1,
    const float* __restrict__ Wr1, const float* __restrict__ b1,
    float* __restrict__ h) {
  __shared__ float As[BK][BM + 4];
  __shared__ float Bs[BK][BN + 4];
  const int br = blockIdx.x;       // 704 row blocks
  const int bn = blockIdx.y;       // 4 col blocks
  const int tid = threadIdx.x;
  const int tx = tid & 15;         // col group (4 cols each)
  const int ty = tid >> 4;         // row group (4 rows each)
  const int r0 = br * BM;
  const int n0 = bn * BN + tx * 4;

  float acc[4][4];
#pragma unroll
  for (int i = 0; i < 4; ++i)
#pragma unroll
    for (int j = 0; j < 4; ++j) acc[i][j] = b1[n0 + j];

  // A-tile loader indices: thread loads A[r0+lr][k0+lk .. +3]
  const int lr = tid >> 2;          // 0..63
  const int lk = (tid & 3) * 4;     // 0,4,8,12
  const float rinv = 1.0f / fmaxf(cnt1[r0 + lr], 1.0f);
  // B-tile loader indices
  const int bk_ = tid >> 4;         // 0..15
  const int bn_ = (tid & 15) * 4;   // 0..60

  for (int phase = 0; phase < 2; ++phase) {
    const float* __restrict__ A = phase ? x : sum1;     // [*][128]
    const float* __restrict__ W = phase ? Wr1 : Wl1;    // [128][256]
    for (int k0 = 0; k0 < IN_C; k0 += BK) {
      float4 av =
          *reinterpret_cast<const float4*>(A + (size_t)(r0 + lr) * IN_C + k0 + lk);
      if (phase == 0) { av.x *= rinv; av.y *= rinv; av.z *= rinv; av.w *= rinv; }
      As[lk + 0][lr] = av.x;
      As[lk + 1][lr] = av.y;
      As[lk + 2][lr] = av.z;
      As[lk + 3][lr] = av.w;
      const float4 wv = *reinterpret_cast<const float4*>(
          W + (size_t)(k0 + bk_) * HID_C + bn * BN + bn_);
      *reinterpret_cast<float4*>(&Bs[bk_][bn_]) = wv;
      __syncthreads();
#pragma unroll
      for (int k = 0; k < BK; ++k) {
        float a[4], b[4];
        *reinterpret_cast<float4*>(a) =
            *reinterpret_cast<const float4*>(&As[k][ty * 4]);
        *reinterpret_cast<float4*>(b) =
            *reinterpret_cast<const float4*>(&Bs[k][tx * 4]);
#pragma unroll
        for (int i = 0; i < 4; ++i)
#pragma unroll
          for (int j = 0; j < 4; ++j) acc[i][j] += a[i] * b[j];
      }
      __syncthreads();
    }
  }
#pragma unroll
  for (int i = 0; i < 4; ++i) {
    float4 o;
    o.x = fmaxf(acc[i][0], 0.0f);
    o.y = fmaxf(acc[i][1], 0.0f);
    o.z = fmaxf(acc[i][2], 0.0f);
    o.w = fmaxf(acc[i][3], 0.0f);
    *reinterpret_cast<float4*>(h + (size_t)(r0 + ty * 4 + i) * HID_C + n0) = o;
  }
}

// ---------------------------------------------------------------------------
// Kernel 3: layer-2 edge scatter. One wave per edge; lane handles 4 channels.
__global__ __launch_bounds__(256) void scatter2(
    const float* __restrict__ h, const int* __restrict__ src,
    const int* __restrict__ dst, float* __restrict__ sum2,
    float* __restrict__ cnt2) {
  const int lane = threadIdx.x & 63;
  const int wave = (blockIdx.x * blockDim.x + threadIdx.x) >> 6;
  const int nwaves = (gridDim.x * blockDim.x) >> 6;
  for (int e = wave; e < E2; e += nwaves) {
    const int s = src[e];
    const int d = dst[e];
    const float4 v =
        *reinterpret_cast<const float4*>(h + (size_t)s * HID_C + lane * 4);
    float* o = sum2 + (size_t)d * HID_C + lane * 4;
    unsafeAtomicAdd(o + 0, v.x);
    unsafeAtomicAdd(o + 1, v.y);
    unsafeAtomicAdd(o + 2, v.z);
    unsafeAtomicAdd(o + 3, v.w);
    if (lane == 0) unsafeAtomicAdd(cnt2 + d, 1.0f);
  }
}

// ---------------------------------------------------------------------------
// Kernel 4: logits = agg2 @ Wl2 + h[:N2_TGT] @ Wr2 + b2
// Block: 4 rows x 64 cols, rows staged in LDS.
__global__ __launch_bounds__(256) void l2_dense(
    const float* __restrict__ sum2, const float* __restrict__ cnt2,
    const float* __restrict__ h, const float* __restrict__ Wl2,
    const float* __restrict__ Wr2, const float* __restrict__ b2,
    float* __restrict__ logits) {
  __shared__ float Aa[4][HID_C];
  __shared__ float Ax[4][HID_C];
  const int tid = threadIdx.x;
  const int rb = blockIdx.x * 4;
  const int lr = tid >> 6;          // 0..3
  const int lk = (tid & 63) * 4;    // 0..252
  const float rinv = 1.0f / fmaxf(cnt2[rb + lr], 1.0f);
  const float4 sa =
      *reinterpret_cast<const float4*>(sum2 + (size_t)(rb + lr) * HID_C + lk);
  Aa[lr][lk + 0] = sa.x * rinv;
  Aa[lr][lk + 1] = sa.y * rinv;
  Aa[lr][lk + 2] = sa.z * rinv;
  Aa[lr][lk + 3] = sa.w * rinv;
  const float4 xa =
      *reinterpret_cast<const float4*>(h + (size_t)(rb + lr) * HID_C + lk);
  *reinterpret_cast<float4*>(&Ax[lr][lk]) = xa;
  __syncthreads();

  const int r = tid >> 6;
  const int n = tid & 63;
  float acc = b2[n];
#pragma unroll 4
  for (int k = 0; k < HID_C; ++k) {
    acc += Aa[r][k] * Wl2[k * OUT_C + n];
    acc += Ax[r][k] * Wr2[k * OUT_C + n];
  }
  logits[(size_t)(rb + r) * OUT_C + n] = acc;
}

// ---------------------------------------------------------------------------
// Kernel 5: log_softmax rows of 64. One wave per row.
__global__ __launch_bounds__(256) void lsm(const float* __restrict__ logits,
                                           float* __restrict__ out) {
  const int lane = threadIdx.x & 63;
  const int row = (blockIdx.x * blockDim.x + threadIdx.x) >> 6;
  if (row >= N2_TGT) return;
  const float v = logits[(size_t)row * OUT_C + lane];
  float m = v;
#pragma unroll
  for (int off = 32; off; off >>= 1) m = fmaxf(m, __shfl_xor(m, off));
  const float e = expf(v - m);
  float s = e;
#pragma unroll
  for (int off = 32; off; off >>= 1) s += __shfl_xor(s, off);
  out[(size_t)row * OUT_C + lane] = v - m - logf(s);
}

// ---------------------------------------------------------------------------
extern "C" void kernel_launch(void* const* d_in, const int* in_sizes, int n_in,
                              void* d_out, int out_size, void* d_ws,
                              size_t ws_size, hipStream_t stream) {
  const float* x   = (const float*)d_in[0];
  const float* Wl1 = (const float*)d_in[1];
  const float* Wr1 = (const float*)d_in[2];
  const float* b1  = (const float*)d_in[3];
  const float* Wl2 = (const float*)d_in[4];
  const float* Wr2 = (const float*)d_in[5];
  const float* b2  = (const float*)d_in[6];
  const int* src1  = (const int*)d_in[7];
  const int* dst1  = (const int*)d_in[8];
  const int* src2  = (const int*)d_in[9];
  const int* dst2  = (const int*)d_in[10];

  float* ws    = (float*)d_ws;
  float* sum1  = ws + OFF_SUM1;
  float* cnt1  = ws + OFF_CNT1;
  float* sum2  = ws + OFF_SUM2;
  float* cnt2  = ws + OFF_CNT2;
  float* h     = ws + OFF_H;
  float* logit = ws + OFF_LOG;
  float* out   = (float*)d_out;

  // zero the accumulator region (sum1|cnt1|sum2|cnt2 are contiguous)
  hipMemsetAsync(d_ws, 0, ZERO_FLOATS * sizeof(float), stream);

  scatter1<<<dim3(4096), dim3(256), 0, stream>>>(x, src1, dst1, sum1, cnt1);
  l1_dense<<<dim3(N1_TGT / BM, HID_C / BN), dim3(256), 0, stream>>>(
      sum1, cnt1, x, Wl1, Wr1, b1, h);
  scatter2<<<dim3(512), dim3(256), 0, stream>>>(h, src2, dst2, sum2, cnt2);
  l2_dense<<<dim3(N2_TGT / 4), dim3(256), 0, stream>>>(sum2, cnt2, h, Wl2, Wr2,
                                                       b2, logit);
  lsm<<<dim3(N2_TGT * 64 / 256), dim3(256), 0, stream>>>(logit, out);
}

// Round 3
// 1026.354 us; speedup vs baseline: 1.7967x; 1.7967x over previous
//
#include <hip/hip_runtime.h>
#include <hip/hip_bf16.h>

// Problem constants (from reference)
constexpr int N1_SRC = 1171456;
constexpr int N1_TGT = 45056;
constexpr int N2_TGT = 4096;
constexpr int E1 = 1126400;
constexpr int E2 = 40960;
constexpr int IN_C = 128;
constexpr int HID_C = 256;
constexpr int OUT_C = 64;

// ---------------------------------------------------------------------------
// Kernel: per-target-node degree histogram
__global__ __launch_bounds__(256) void hist(const int* __restrict__ dst,
                                            int* __restrict__ cnt, int E) {
  const int i = blockIdx.x * blockDim.x + threadIdx.x;
  if (i < E) atomicAdd(&cnt[dst[i]], 1);
}

// ---------------------------------------------------------------------------
// Kernel: exclusive prefix scan (single workgroup, 1024 threads, chunked)
__global__ __launch_bounds__(1024) void scan_excl(const int* __restrict__ cnt,
                                                  int* __restrict__ off, int n) {
  const int tid = threadIdx.x;
  const int lane = tid & 63;
  const int wv = tid >> 6;  // 0..15
  __shared__ int wsum[16];
  __shared__ int carry_s;
  if (tid == 0) carry_s = 0;
  __syncthreads();
  for (int base = 0; base < n; base += 1024) {
    const int i = base + tid;
    const int v = (i < n) ? cnt[i] : 0;
    // inclusive scan within wave
    int s = v;
#pragma unroll
    for (int o = 1; o < 64; o <<= 1) {
      const int t = __shfl_up(s, o);
      if (lane >= o) s += t;
    }
    if (lane == 63) wsum[wv] = s;
    __syncthreads();
    if (wv == 0 && lane < 16) {
      const int ws = wsum[lane];
      int ss = ws;
#pragma unroll
      for (int o = 1; o < 16; o <<= 1) {
        const int t = __shfl_up(ss, o);
        if (lane >= o) ss += t;
      }
      wsum[lane] = ss - ws;  // exclusive wave offset
    }
    __syncthreads();
    const int excl = carry_s + wsum[wv] + (s - v);
    if (i < n) off[i] = excl;
    __syncthreads();
    if (tid == 1023) carry_s += wsum[15] + s;  // total of this chunk
    __syncthreads();
  }
}

// ---------------------------------------------------------------------------
// Kernel: scatter edge source-ids into CSR buckets
__global__ __launch_bounds__(256) void fill_csr(
    const int* __restrict__ src, const int* __restrict__ dst,
    const int* __restrict__ off, int* __restrict__ cur,
    int* __restrict__ eidx, int E) {
  const int i = blockIdx.x * blockDim.x + threadIdx.x;
  if (i < E) {
    const int d = dst[i];
    const int p = atomicAdd(&cur[d], 1);
    eidx[off[d] + p] = src[i];
  }
}

// ---------------------------------------------------------------------------
// Kernel: mean-aggregate neighbor rows. One block per node, one thread/channel.
template <int C>
__global__ __launch_bounds__(C) void gather_mean(
    const float* __restrict__ x, const int* __restrict__ eidx,
    const int* __restrict__ off, const int* __restrict__ cnt,
    float* __restrict__ agg) {
  const int node = blockIdx.x;
  const int c = threadIdx.x;
  const int beg = off[node];
  const int deg = cnt[node];
  float s0 = 0.f, s1 = 0.f, s2 = 0.f, s3 = 0.f;
  int i = 0;
  for (; i + 4 <= deg; i += 4) {
    const int n0 = eidx[beg + i + 0];
    const int n1 = eidx[beg + i + 1];
    const int n2 = eidx[beg + i + 2];
    const int n3 = eidx[beg + i + 3];
    s0 += x[(size_t)n0 * C + c];
    s1 += x[(size_t)n1 * C + c];
    s2 += x[(size_t)n2 * C + c];
    s3 += x[(size_t)n3 * C + c];
  }
  for (; i < deg; ++i) s0 += x[(size_t)eidx[beg + i] * C + c];
  const float s = (s0 + s1) + (s2 + s3);
  agg[(size_t)node * C + c] = s / (float)(deg > 0 ? deg : 1);
}

// ---------------------------------------------------------------------------
// Kernel: h = relu(agg1 @ Wl1 + x[:N1_TGT] @ Wr1 + b1)
// Tiled fp32 GEMM: BM=64 x BN=64, 256 threads, 4x4 per thread, K staged in LDS.
constexpr int BM = 64, BN = 64, BK = 16;
__global__ __launch_bounds__(256) void l1_dense(
    const float* __restrict__ agg1, const float* __restrict__ x,
    const float* __restrict__ Wl1, const float* __restrict__ Wr1,
    const float* __restrict__ b1, float* __restrict__ h) {
  __shared__ float As[BK][BM + 4];
  __shared__ float Bs[BK][BN + 4];
  const int br = blockIdx.x;
  const int bn = blockIdx.y;
  const int tid = threadIdx.x;
  const int tx = tid & 15;
  const int ty = tid >> 4;
  const int r0 = br * BM;
  const int n0 = bn * BN + tx * 4;

  float acc[4][4];
#pragma unroll
  for (int i = 0; i < 4; ++i)
#pragma unroll
    for (int j = 0; j < 4; ++j) acc[i][j] = b1[n0 + j];

  const int lr = tid >> 2;
  const int lk = (tid & 3) * 4;
  const int bk_ = tid >> 4;
  const int bn_ = (tid & 15) * 4;

  for (int phase = 0; phase < 2; ++phase) {
    const float* __restrict__ A = phase ? x : agg1;    // [*][128]
    const float* __restrict__ W = phase ? Wr1 : Wl1;   // [128][256]
    for (int k0 = 0; k0 < IN_C; k0 += BK) {
      const float4 av =
          *reinterpret_cast<const float4*>(A + (size_t)(r0 + lr) * IN_C + k0 + lk);
      As[lk + 0][lr] = av.x;
      As[lk + 1][lr] = av.y;
      As[lk + 2][lr] = av.z;
      As[lk + 3][lr] = av.w;
      const float4 wv = *reinterpret_cast<const float4*>(
          W + (size_t)(k0 + bk_) * HID_C + bn * BN + bn_);
      *reinterpret_cast<float4*>(&Bs[bk_][bn_]) = wv;
      __syncthreads();
#pragma unroll
      for (int k = 0; k < BK; ++k) {
        float a[4], b[4];
        *reinterpret_cast<float4*>(a) =
            *reinterpret_cast<const float4*>(&As[k][ty * 4]);
        *reinterpret_cast<float4*>(b) =
            *reinterpret_cast<const float4*>(&Bs[k][tx * 4]);
#pragma unroll
        for (int i = 0; i < 4; ++i)
#pragma unroll
          for (int j = 0; j < 4; ++j) acc[i][j] += a[i] * b[j];
      }
      __syncthreads();
    }
  }
#pragma unroll
  for (int i = 0; i < 4; ++i) {
    float4 o;
    o.x = fmaxf(acc[i][0], 0.0f);
    o.y = fmaxf(acc[i][1], 0.0f);
    o.z = fmaxf(acc[i][2], 0.0f);
    o.w = fmaxf(acc[i][3], 0.0f);
    *reinterpret_cast<float4*>(h + (size_t)(r0 + ty * 4 + i) * HID_C + n0) = o;
  }
}

// ---------------------------------------------------------------------------
// Kernel: out = log_softmax(agg2 @ Wl2 + h[:N2_TGT] @ Wr2 + b2)
// Block: 4 rows x 64 cols; each wave owns one row -> shfl log-softmax fused.
__global__ __launch_bounds__(256) void l2_dense_lsm(
    const float* __restrict__ agg2, const float* __restrict__ h,
    const float* __restrict__ Wl2, const float* __restrict__ Wr2,
    const float* __restrict__ b2, float* __restrict__ out) {
  __shared__ float Aa[4][HID_C];
  __shared__ float Ax[4][HID_C];
  const int tid = threadIdx.x;
  const int rb = blockIdx.x * 4;
  const int lr = tid >> 6;
  const int lk = (tid & 63) * 4;
  const float4 sa =
      *reinterpret_cast<const float4*>(agg2 + (size_t)(rb + lr) * HID_C + lk);
  *reinterpret_cast<float4*>(&Aa[lr][lk]) = sa;
  const float4 xa =
      *reinterpret_cast<const float4*>(h + (size_t)(rb + lr) * HID_C + lk);
  *reinterpret_cast<float4*>(&Ax[lr][lk]) = xa;
  __syncthreads();

  const int r = tid >> 6;   // wave index == row
  const int n = tid & 63;   // lane == col
  float acc = b2[n];
#pragma unroll 4
  for (int k = 0; k < HID_C; ++k) {
    acc += Aa[r][k] * Wl2[k * OUT_C + n];
    acc += Ax[r][k] * Wr2[k * OUT_C + n];
  }
  // log-softmax across the wave's 64 lanes
  float m = acc;
#pragma unroll
  for (int o = 32; o; o >>= 1) m = fmaxf(m, __shfl_xor(m, o));
  const float e = expf(acc - m);
  float ssum = e;
#pragma unroll
  for (int o = 32; o; o >>= 1) ssum += __shfl_xor(ssum, o);
  out[(size_t)(rb + r) * OUT_C + n] = acc - m - logf(ssum);
}

// ---------------------------------------------------------------------------
extern "C" void kernel_launch(void* const* d_in, const int* in_sizes, int n_in,
                              void* d_out, int out_size, void* d_ws,
                              size_t ws_size, hipStream_t stream) {
  const float* x   = (const float*)d_in[0];
  const float* Wl1 = (const float*)d_in[1];
  const float* Wr1 = (const float*)d_in[2];
  const float* b1  = (const float*)d_in[3];
  const float* Wl2 = (const float*)d_in[4];
  const float* Wr2 = (const float*)d_in[5];
  const float* b2  = (const float*)d_in[6];
  const int* src1  = (const int*)d_in[7];
  const int* dst1  = (const int*)d_in[8];
  const int* src2  = (const int*)d_in[9];
  const int* dst2  = (const int*)d_in[10];

  // Workspace layout (all 4-byte elems). agg2 aliases agg1 (dead after
  // l1_dense); total ~74.5 MB.
  int* cnt1i = (int*)d_ws;                  // [N1_TGT]
  int* cur1  = cnt1i + N1_TGT;              // [N1_TGT]
  int* cnt2i = cur1 + N1_TGT;               // [N2_TGT]
  int* cur2  = cnt2i + N2_TGT;              // [N2_TGT]
  int* off1  = cur2 + N2_TGT;               // [N1_TGT]
  int* off2  = off1 + N1_TGT;               // [N2_TGT]
  int* eidx2 = off2 + N2_TGT;               // [E2]
  int* eidx1 = eidx2 + E2;                  // [E1]
  float* agg1 = (float*)(eidx1 + E1);       // [N1_TGT*IN_C]
  float* agg2 = agg1;                       // [N2_TGT*HID_C] (alias, disjoint in time)
  float* h    = agg1 + (size_t)N1_TGT * IN_C;  // [N1_TGT*HID_C]
  float* out  = (float*)d_out;

  // zero histogram counters + cursors (contiguous at ws start)
  hipMemsetAsync(d_ws, 0, (size_t)(2 * N1_TGT + 2 * N2_TGT) * sizeof(int),
                 stream);

  // ---- layer 1 CSR build + gather + dense
  hist<<<dim3((E1 + 255) / 256), dim3(256), 0, stream>>>(dst1, cnt1i, E1);
  scan_excl<<<dim3(1), dim3(1024), 0, stream>>>(cnt1i, off1, N1_TGT);
  fill_csr<<<dim3((E1 + 255) / 256), dim3(256), 0, stream>>>(src1, dst1, off1,
                                                             cur1, eidx1, E1);
  gather_mean<IN_C><<<dim3(N1_TGT), dim3(IN_C), 0, stream>>>(x, eidx1, off1,
                                                             cnt1i, agg1);
  l1_dense<<<dim3(N1_TGT / BM, HID_C / BN), dim3(256), 0, stream>>>(
      agg1, x, Wl1, Wr1, b1, h);

  // ---- layer 2 CSR build + gather + dense(+log_softmax)
  hist<<<dim3((E2 + 255) / 256), dim3(256), 0, stream>>>(dst2, cnt2i, E2);
  scan_excl<<<dim3(1), dim3(1024), 0, stream>>>(cnt2i, off2, N2_TGT);
  fill_csr<<<dim3((E2 + 255) / 256), dim3(256), 0, stream>>>(src2, dst2, off2,
                                                             cur2, eidx2, E2);
  gather_mean<HID_C><<<dim3(N2_TGT), dim3(HID_C), 0, stream>>>(h, eidx2, off2,
                                                               cnt2i, agg2);
  l2_dense_lsm<<<dim3(N2_TGT / 4), dim3(256), 0, stream>>>(agg2, h, Wl2, Wr2,
                                                           b2, out);
}

// Round 4
// 937.070 us; speedup vs baseline: 1.9679x; 1.0953x over previous
//
#include <hip/hip_runtime.h>
#include <hip/hip_bf16.h>

// Problem constants (from reference)
constexpr int N1_SRC = 1171456;
constexpr int N1_TGT = 45056;
constexpr int N2_TGT = 4096;
constexpr int E1 = 1126400;
constexpr int E2 = 40960;
constexpr int IN_C = 128;
constexpr int HID_C = 256;
constexpr int OUT_C = 64;
constexpr int KV = 256;  // virtual K for layer-1 GEMM: [agg | x]

typedef __attribute__((ext_vector_type(8))) short bf16x8;
typedef __attribute__((ext_vector_type(4))) float f32x4;

__device__ __forceinline__ unsigned f2bf(float f) {
  unsigned u = __float_as_uint(f);
  return (u + 0x7FFFu + ((u >> 16) & 1u)) >> 16;  // RNE
}
__device__ __forceinline__ float bf2f(unsigned u) {
  return __uint_as_float(u << 16);
}

// ---------------------------------------------------------------------------
// degree histogram
__global__ __launch_bounds__(256) void hist(const int* __restrict__ dst,
                                            int* __restrict__ cnt, int E) {
  const int i = blockIdx.x * blockDim.x + threadIdx.x;
  if (i < E) atomicAdd(&cnt[dst[i]], 1);
}

// ---------------------------------------------------------------------------
// hierarchical exclusive scan: per-1024-block scan + partials
__global__ __launch_bounds__(1024) void scan_block(const int* __restrict__ cnt,
                                                   int* __restrict__ off,
                                                   int* __restrict__ partials,
                                                   int n) {
  const int tid = threadIdx.x, lane = tid & 63, wv = tid >> 6;
  __shared__ int wsum[16];
  const int i = blockIdx.x * 1024 + tid;
  const int v = (i < n) ? cnt[i] : 0;
  int s = v;
#pragma unroll
  for (int o = 1; o < 64; o <<= 1) {
    const int t = __shfl_up(s, o);
    if (lane >= o) s += t;
  }
  if (lane == 63) wsum[wv] = s;
  __syncthreads();
  if (wv == 0 && lane < 16) {
    const int ws = wsum[lane];
    int ss = ws;
#pragma unroll
    for (int o = 1; o < 16; o <<= 1) {
      const int t = __shfl_up(ss, o);
      if (lane >= o) ss += t;
    }
    wsum[lane] = ss - ws;  // exclusive wave offsets
  }
  __syncthreads();
  if (i < n) off[i] = wsum[wv] + s - v;
  if (tid == 1023) partials[blockIdx.x] = wsum[15] + s;
}

__global__ __launch_bounds__(64) void scan_partials(int* __restrict__ p, int nb) {
  const int t = threadIdx.x;
  const int v = (t < nb) ? p[t] : 0;
  int s = v;
#pragma unroll
  for (int o = 1; o < 64; o <<= 1) {
    const int tt = __shfl_up(s, o);
    if (t >= o) s += tt;
  }
  if (t < nb) p[t] = s - v;  // exclusive
}

__global__ __launch_bounds__(256) void scan_add(int* __restrict__ off,
                                                const int* __restrict__ p, int n) {
  const int i = blockIdx.x * 256 + threadIdx.x;
  if (i < n) off[i] += p[i >> 10];
}

// ---------------------------------------------------------------------------
// scatter edge source-ids into CSR buckets
__global__ __launch_bounds__(256) void fill_csr(
    const int* __restrict__ src, const int* __restrict__ dst,
    const int* __restrict__ off, int* __restrict__ cur,
    int* __restrict__ eidx, int E) {
  const int i = blockIdx.x * blockDim.x + threadIdx.x;
  if (i < E) {
    const int d = dst[i];
    const int p = atomicAdd(&cur[d], 1);
    eidx[off[d] + p] = src[i];
  }
}

// ---------------------------------------------------------------------------
// W1 prep: Bt[n][k] bf16, k<128 -> Wl1[k][n], else Wr1[k-128][n]
__global__ __launch_bounds__(256) void prep_w1(const float* __restrict__ Wl1,
                                               const float* __restrict__ Wr1,
                                               unsigned short* __restrict__ Bt) {
  const int idx = blockIdx.x * 256 + threadIdx.x;  // 0..65535
  const int k = idx & 255, n = idx >> 8;
  const float w = (k < IN_C) ? Wl1[k * HID_C + n] : Wr1[(k - IN_C) * HID_C + n];
  Bt[n * KV + k] = (unsigned short)f2bf(w);
}

// W2 prep: transposed fp32 copies Wl2t/Wr2t [64][256]
__global__ __launch_bounds__(256) void prep_w2(const float* __restrict__ Wl2,
                                               const float* __restrict__ Wr2,
                                               float* __restrict__ Wl2t,
                                               float* __restrict__ Wr2t) {
  const int idx = blockIdx.x * 256 + threadIdx.x;  // 0..16383
  const int k = idx & 255, n = idx >> 8;
  Wl2t[n * HID_C + k] = Wl2[k * OUT_C + n];
  Wr2t[n * HID_C + k] = Wr2[k * OUT_C + n];
}

// x[:N1_TGT] fp32 -> bf16 into Ab[:, 128:256]
__global__ __launch_bounds__(256) void conv_x(const float* __restrict__ x,
                                              unsigned short* __restrict__ Ab) {
  const size_t idx = (size_t)(blockIdx.x * 256 + threadIdx.x) * 4;
  const int m = (int)(idx >> 7);
  const int c = (int)(idx & 127);
  const float4 v = *reinterpret_cast<const float4*>(x + (size_t)m * IN_C + c);
  uint2 o;
  o.x = f2bf(v.x) | (f2bf(v.y) << 16);
  o.y = f2bf(v.z) | (f2bf(v.w) << 16);
  *reinterpret_cast<uint2*>(Ab + (size_t)m * KV + IN_C + c) = o;
}

// ---------------------------------------------------------------------------
// layer-1 mean-gather, writes bf16 into Ab[:, 0:128]. Wave per node.
__global__ __launch_bounds__(256) void gather1(
    const float* __restrict__ x, const int* __restrict__ eidx,
    const int* __restrict__ off, const int* __restrict__ cnt,
    unsigned short* __restrict__ Ab) {
  const int lane = threadIdx.x & 63;
  const int node = blockIdx.x * 4 + (threadIdx.x >> 6);
  const int beg = off[node];
  const int deg = cnt[node];
  float s0 = 0, s1 = 0, t0 = 0, t1 = 0, u0 = 0, u1 = 0, v0 = 0, v1 = 0;
  int i = 0;
  for (; i + 4 <= deg; i += 4) {
    const int n0 = eidx[beg + i + 0];
    const int n1 = eidx[beg + i + 1];
    const int n2 = eidx[beg + i + 2];
    const int n3 = eidx[beg + i + 3];
    const float2 a = *reinterpret_cast<const float2*>(x + (size_t)n0 * IN_C + lane * 2);
    const float2 b = *reinterpret_cast<const float2*>(x + (size_t)n1 * IN_C + lane * 2);
    const float2 c = *reinterpret_cast<const float2*>(x + (size_t)n2 * IN_C + lane * 2);
    const float2 d = *reinterpret_cast<const float2*>(x + (size_t)n3 * IN_C + lane * 2);
    s0 += a.x; s1 += a.y; t0 += b.x; t1 += b.y;
    u0 += c.x; u1 += c.y; v0 += d.x; v1 += d.y;
  }
  for (; i < deg; ++i) {
    const int n0 = eidx[beg + i];
    const float2 a = *reinterpret_cast<const float2*>(x + (size_t)n0 * IN_C + lane * 2);
    s0 += a.x; s1 += a.y;
  }
  const float inv = 1.0f / (float)(deg > 0 ? deg : 1);
  const float c0 = (s0 + t0 + u0 + v0) * inv;
  const float c1 = (s1 + t1 + u1 + v1) * inv;
  *reinterpret_cast<unsigned*>(Ab + (size_t)node * KV + lane * 2) =
      f2bf(c0) | (f2bf(c1) << 16);
}

// ---------------------------------------------------------------------------
// layer-1 GEMM via bf16 MFMA: h = relu(A[45056x256] @ B[256x256] + b1), bf16 out.
// Block: 64 rows x 256 cols, 4 waves each 64x64. K-step 32 (one MFMA K).
__global__ __launch_bounds__(256) void l1_gemm(
    const unsigned short* __restrict__ Ab, const unsigned short* __restrict__ Bt,
    const float* __restrict__ b1, unsigned short* __restrict__ h_bf) {
  __shared__ unsigned short As[64 * 40];    // padded stride 40 bf16 = 80 B
  __shared__ unsigned short Bs[256 * 40];
  const int tid = threadIdx.x;
  const int lane = tid & 63;
  const int w = tid >> 6;
  const int r0 = blockIdx.x * 64;
  const int wn = w * 64;
  f32x4 acc[4][4] = {};  // [mi][nj]
  const int arow = tid >> 2;
  const int akoff = (tid & 3) * 8;
  for (int ks = 0; ks < 8; ++ks) {
    const int k0 = ks * 32;
    if (ks) __syncthreads();
    const bf16x8 av =
        *reinterpret_cast<const bf16x8*>(Ab + (size_t)(r0 + arow) * KV + k0 + akoff);
    *reinterpret_cast<bf16x8*>(As + arow * 40 + akoff) = av;
#pragma unroll
    for (int it = 0; it < 4; ++it) {
      const int chunk = it * 256 + tid;
      const int n = chunk >> 2;
      const int koff = (chunk & 3) * 8;
      const bf16x8 bv =
          *reinterpret_cast<const bf16x8*>(Bt + (size_t)n * KV + k0 + koff);
      *reinterpret_cast<bf16x8*>(Bs + n * 40 + koff) = bv;
    }
    __syncthreads();
    const int kg = (lane >> 4) * 8;
    const int rl = lane & 15;
    bf16x8 af[4], bfr[4];
#pragma unroll
    for (int mi = 0; mi < 4; ++mi)
      af[mi] = *reinterpret_cast<const bf16x8*>(As + (mi * 16 + rl) * 40 + kg);
#pragma unroll
    for (int nj = 0; nj < 4; ++nj)
      bfr[nj] =
          *reinterpret_cast<const bf16x8*>(Bs + (wn + nj * 16 + rl) * 40 + kg);
#pragma unroll
    for (int mi = 0; mi < 4; ++mi)
#pragma unroll
      for (int nj = 0; nj < 4; ++nj)
        acc[mi][nj] = __builtin_amdgcn_mfma_f32_16x16x32_bf16(
            af[mi], bfr[nj], acc[mi][nj], 0, 0, 0);
  }
  const int rl = lane & 15;
  const int rg = lane >> 4;
#pragma unroll
  for (int nj = 0; nj < 4; ++nj) {
    const int gcol = wn + nj * 16 + rl;
    const float bias = b1[gcol];
#pragma unroll
    for (int mi = 0; mi < 4; ++mi)
#pragma unroll
      for (int r = 0; r < 4; ++r) {
        const int grow = r0 + mi * 16 + rg * 4 + r;
        const float v = fmaxf(acc[mi][nj][r] + bias, 0.0f);
        h_bf[(size_t)grow * HID_C + gcol] = (unsigned short)f2bf(v);
      }
  }
}

// ---------------------------------------------------------------------------
// layer-2 mean-gather from bf16 h. Wave per node, 4 ch/lane.
__global__ __launch_bounds__(256) void gather2(
    const unsigned short* __restrict__ h_bf, const int* __restrict__ eidx,
    const int* __restrict__ off, const int* __restrict__ cnt,
    float* __restrict__ agg2) {
  const int lane = threadIdx.x & 63;
  const int node = blockIdx.x * 4 + (threadIdx.x >> 6);
  const int beg = off[node];
  const int deg = cnt[node];
  float a0 = 0, a1 = 0, a2 = 0, a3 = 0, b0 = 0, b1v = 0, b2v = 0, b3 = 0;
  int i = 0;
  for (; i + 2 <= deg; i += 2) {
    const int n0 = eidx[beg + i], n1 = eidx[beg + i + 1];
    const uint2 ra =
        *reinterpret_cast<const uint2*>(h_bf + (size_t)n0 * HID_C + lane * 4);
    const uint2 rb =
        *reinterpret_cast<const uint2*>(h_bf + (size_t)n1 * HID_C + lane * 4);
    a0 += bf2f(ra.x & 0xffff); a1 += bf2f(ra.x >> 16);
    a2 += bf2f(ra.y & 0xffff); a3 += bf2f(ra.y >> 16);
    b0 += bf2f(rb.x & 0xffff); b1v += bf2f(rb.x >> 16);
    b2v += bf2f(rb.y & 0xffff); b3 += bf2f(rb.y >> 16);
  }
  if (i < deg) {
    const int n0 = eidx[beg + i];
    const uint2 ra =
        *reinterpret_cast<const uint2*>(h_bf + (size_t)n0 * HID_C + lane * 4);
    a0 += bf2f(ra.x & 0xffff); a1 += bf2f(ra.x >> 16);
    a2 += bf2f(ra.y & 0xffff); a3 += bf2f(ra.y >> 16);
  }
  const float inv = 1.0f / (float)(deg > 0 ? deg : 1);
  float4 o;
  o.x = (a0 + b0) * inv; o.y = (a1 + b1v) * inv;
  o.z = (a2 + b2v) * inv; o.w = (a3 + b3) * inv;
  *reinterpret_cast<float4*>(agg2 + (size_t)node * HID_C + lane * 4) = o;
}

// ---------------------------------------------------------------------------
// out = log_softmax(agg2 @ Wl2 + h[:4096] @ Wr2 + b2). 16 rows/block.
__global__ __launch_bounds__(256) void l2_dense_lsm(
    const float* __restrict__ agg2, const unsigned short* __restrict__ h_bf,
    const float* __restrict__ Wl2t, const float* __restrict__ Wr2t,
    const float* __restrict__ b2, float* __restrict__ out) {
  __shared__ float Aa[16][HID_C];
  __shared__ float Ax[16][HID_C];
  const int tid = threadIdx.x;
  const int rb = blockIdx.x * 16;
#pragma unroll
  for (int it = 0; it < 4; ++it) {
    const int e = (it * 256 + tid) * 4;
    const int row = e >> 8, c = e & 255;
    *reinterpret_cast<float4*>(&Aa[row][c]) =
        *reinterpret_cast<const float4*>(agg2 + (size_t)(rb + row) * HID_C + c);
  }
#pragma unroll
  for (int it = 0; it < 2; ++it) {
    const int e = (it * 256 + tid) * 8;
    const int row = e >> 8, c = e & 255;
    const uint4 raw =
        *reinterpret_cast<const uint4*>(h_bf + (size_t)(rb + row) * HID_C + c);
    Ax[row][c + 0] = bf2f(raw.x & 0xffff); Ax[row][c + 1] = bf2f(raw.x >> 16);
    Ax[row][c + 2] = bf2f(raw.y & 0xffff); Ax[row][c + 3] = bf2f(raw.y >> 16);
    Ax[row][c + 4] = bf2f(raw.z & 0xffff); Ax[row][c + 5] = bf2f(raw.z >> 16);
    Ax[row][c + 6] = bf2f(raw.w & 0xffff); Ax[row][c + 7] = bf2f(raw.w >> 16);
  }
  __syncthreads();
  const int n = tid & 63, rg = tid >> 6;
  const float bias = b2[n];
  float acc[4] = {bias, bias, bias, bias};
  for (int k = 0; k < HID_C; k += 4) {
    const float4 wl = *reinterpret_cast<const float4*>(Wl2t + n * HID_C + k);
    const float4 wr = *reinterpret_cast<const float4*>(Wr2t + n * HID_C + k);
#pragma unroll
    for (int i = 0; i < 4; ++i) {
      const float4 av = *reinterpret_cast<const float4*>(&Aa[rg * 4 + i][k]);
      const float4 xv = *reinterpret_cast<const float4*>(&Ax[rg * 4 + i][k]);
      acc[i] += av.x * wl.x + av.y * wl.y + av.z * wl.z + av.w * wl.w +
                xv.x * wr.x + xv.y * wr.y + xv.z * wr.z + xv.w * wr.w;
    }
  }
#pragma unroll
  for (int i = 0; i < 4; ++i) {
    const float v = acc[i];
    float m = v;
#pragma unroll
    for (int o = 32; o; o >>= 1) m = fmaxf(m, __shfl_xor(m, o));
    const float e = expf(v - m);
    float s = e;
#pragma unroll
    for (int o = 32; o; o >>= 1) s += __shfl_xor(s, o);
    out[(size_t)(rb + rg * 4 + i) * OUT_C + n] = v - m - logf(s);
  }
}

// ---------------------------------------------------------------------------
extern "C" void kernel_launch(void* const* d_in, const int* in_sizes, int n_in,
                              void* d_out, int out_size, void* d_ws,
                              size_t ws_size, hipStream_t stream) {
  const float* x   = (const float*)d_in[0];
  const float* Wl1 = (const float*)d_in[1];
  const float* Wr1 = (const float*)d_in[2];
  const float* b1  = (const float*)d_in[3];
  const float* Wl2 = (const float*)d_in[4];
  const float* Wr2 = (const float*)d_in[5];
  const float* b2  = (const float*)d_in[6];
  const int* src1  = (const int*)d_in[7];
  const int* dst1  = (const int*)d_in[8];
  const int* src2  = (const int*)d_in[9];
  const int* dst2  = (const int*)d_in[10];

  // Workspace layout (byte offsets; all regions 16B-aligned)
  char* p = (char*)d_ws;
  int* cnt1 = (int*)p;                 p += (size_t)N1_TGT * 4;
  int* cur1 = (int*)p;                 p += (size_t)N1_TGT * 4;
  int* cnt2 = (int*)p;                 p += (size_t)N2_TGT * 4;
  int* cur2 = (int*)p;                 p += (size_t)N2_TGT * 4;
  const size_t zero_bytes = (size_t)(2 * N1_TGT + 2 * N2_TGT) * 4;
  int* off1 = (int*)p;                 p += (size_t)N1_TGT * 4;
  int* off2 = (int*)p;                 p += (size_t)N2_TGT * 4;
  int* part1 = (int*)p;                p += 64 * 4;
  int* part2 = (int*)p;                p += 64 * 4;
  int* eidx1 = (int*)p;                p += (size_t)E1 * 4;
  int* eidx2 = (int*)p;                p += (size_t)E2 * 4;
  unsigned short* Bt = (unsigned short*)p;   p += (size_t)HID_C * KV * 2;
  unsigned short* Ab = (unsigned short*)p;   p += (size_t)N1_TGT * KV * 2;
  unsigned short* h_bf = (unsigned short*)p; p += (size_t)N1_TGT * HID_C * 2;
  float* agg2 = (float*)p;             p += (size_t)N2_TGT * HID_C * 4;
  float* Wl2t = (float*)p;             p += (size_t)OUT_C * HID_C * 4;
  float* Wr2t = (float*)p;             p += (size_t)OUT_C * HID_C * 4;
  float* out = (float*)d_out;

  hipMemsetAsync(d_ws, 0, zero_bytes, stream);

  // weight prep + x conversion
  prep_w1<<<dim3(256), dim3(256), 0, stream>>>(Wl1, Wr1, Bt);
  prep_w2<<<dim3(64), dim3(256), 0, stream>>>(Wl2, Wr2, Wl2t, Wr2t);
  conv_x<<<dim3(5632), dim3(256), 0, stream>>>(x, Ab);

  // ---- layer 1: CSR build + gather + GEMM
  hist<<<dim3((E1 + 255) / 256), dim3(256), 0, stream>>>(dst1, cnt1, E1);
  scan_block<<<dim3(44), dim3(1024), 0, stream>>>(cnt1, off1, part1, N1_TGT);
  scan_partials<<<dim3(1), dim3(64), 0, stream>>>(part1, 44);
  scan_add<<<dim3(176), dim3(256), 0, stream>>>(off1, part1, N1_TGT);
  fill_csr<<<dim3((E1 + 255) / 256), dim3(256), 0, stream>>>(src1, dst1, off1,
                                                             cur1, eidx1, E1);
  gather1<<<dim3(N1_TGT / 4), dim3(256), 0, stream>>>(x, eidx1, off1, cnt1, Ab);
  l1_gemm<<<dim3(N1_TGT / 64), dim3(256), 0, stream>>>(Ab, Bt, b1, h_bf);

  // ---- layer 2: CSR build + gather + dense(+log_softmax)
  hist<<<dim3((E2 + 255) / 256), dim3(256), 0, stream>>>(dst2, cnt2, E2);
  scan_block<<<dim3(4), dim3(1024), 0, stream>>>(cnt2, off2, part2, N2_TGT);
  scan_partials<<<dim3(1), dim3(64), 0, stream>>>(part2, 4);
  scan_add<<<dim3(16), dim3(256), 0, stream>>>(off2, part2, N2_TGT);
  fill_csr<<<dim3((E2 + 255) / 256), dim3(256), 0, stream>>>(src2, dst2, off2,
                                                             cur2, eidx2, E2);
  gather2<<<dim3(N2_TGT / 4), dim3(256), 0, stream>>>(h_bf, eidx2, off2, cnt2,
                                                      agg2);
  l2_dense_lsm<<<dim3(N2_TGT / 16), dim3(256), 0, stream>>>(agg2, h_bf, Wl2t,
                                                            Wr2t, b2, out);
}

// Round 9
// 923.968 us; speedup vs baseline: 1.9958x; 1.0142x over previous
//
#include <hip/hip_runtime.h>
#include <hip/hip_bf16.h>

// Problem constants (from reference)
constexpr int N1_SRC = 1171456;
constexpr int N1_TGT = 45056;
constexpr int N2_TGT = 4096;
constexpr int E1 = 1126400;
constexpr int E2 = 40960;
constexpr int IN_C = 128;
constexpr int HID_C = 256;
constexpr int OUT_C = 64;
constexpr int KV = 256;   // layer-1 GEMM K: [agg | x]
constexpr int KV2 = 512;  // layer-2 GEMM K: [agg2 | h]

typedef __attribute__((ext_vector_type(8))) short bf16x8;
typedef __attribute__((ext_vector_type(4))) float f32x4;

__device__ __forceinline__ unsigned f2bf(float f) {
  unsigned u = __float_as_uint(f);
  return (u + 0x7FFFu + ((u >> 16) & 1u)) >> 16;  // RNE
}
__device__ __forceinline__ float bf2f(unsigned u) {
  return __uint_as_float(u << 16);
}

// ---------------------------------------------------------------------------
// combined degree histogram (both layers)
__global__ __launch_bounds__(256) void hist2(const int* __restrict__ dst1,
                                             const int* __restrict__ dst2,
                                             int* __restrict__ cnt1,
                                             int* __restrict__ cnt2) {
  const int i = blockIdx.x * 256 + threadIdx.x;
  if (i < E1) {
    atomicAdd(&cnt1[dst1[i]], 1);
  } else {
    const int j = i - E1;
    if (j < E2) atomicAdd(&cnt2[dst2[j]], 1);
  }
}

// ---------------------------------------------------------------------------
// per-1024-block scan, both layers (blocks 0..43 -> L1, 44..47 -> L2)
__global__ __launch_bounds__(1024) void scan_block2(
    const int* __restrict__ cnt1, int* __restrict__ off1,
    int* __restrict__ part1, const int* __restrict__ cnt2,
    int* __restrict__ off2, int* __restrict__ part2) {
  const int b = blockIdx.x;
  const int* cnt;
  int *off, *part;
  int lb;
  if (b < 44) { cnt = cnt1; off = off1; part = part1; lb = b; }
  else        { cnt = cnt2; off = off2; part = part2; lb = b - 44; }
  const int tid = threadIdx.x, lane = tid & 63, wv = tid >> 6;
  __shared__ int wsum[16];
  const int i = lb * 1024 + tid;
  const int v = cnt[i];
  int s = v;
#pragma unroll
  for (int o = 1; o < 64; o <<= 1) {
    const int t = __shfl_up(s, o);
    if (lane >= o) s += t;
  }
  if (lane == 63) wsum[wv] = s;
  __syncthreads();
  if (wv == 0 && lane < 16) {
    const int ws = wsum[lane];
    int ss = ws;
#pragma unroll
    for (int o = 1; o < 16; o <<= 1) {
      const int t = __shfl_up(ss, o);
      if (lane >= o) ss += t;
    }
    wsum[lane] = ss - ws;  // exclusive wave offsets
  }
  __syncthreads();
  off[i] = wsum[wv] + s - v;
  if (tid == 1023) part[lb] = wsum[15] + s;
}

__global__ __launch_bounds__(128) void scan_partials2(int* __restrict__ part1,
                                                      int* __restrict__ part2) {
  const int wv = threadIdx.x >> 6, t = threadIdx.x & 63;
  int* p = wv ? part2 : part1;
  const int nb = wv ? 4 : 44;
  const int v = (t < nb) ? p[t] : 0;
  int s = v;
#pragma unroll
  for (int o = 1; o < 64; o <<= 1) {
    const int tt = __shfl_up(s, o);
    if (t >= o) s += tt;
  }
  if (t < nb) p[t] = s - v;  // exclusive
}

__global__ __launch_bounds__(256) void scan_add2(int* __restrict__ off1,
                                                 const int* __restrict__ part1,
                                                 int* __restrict__ off2,
                                                 const int* __restrict__ part2) {
  const int b = blockIdx.x;
  if (b < 176) {
    const int i = b * 256 + threadIdx.x;
    off1[i] += part1[i >> 10];
  } else {
    const int i = (b - 176) * 256 + threadIdx.x;
    off2[i] += part2[i >> 10];
  }
}

// ---------------------------------------------------------------------------
// combined CSR bucket fill (both layers)
__global__ __launch_bounds__(256) void fill2(
    const int* __restrict__ src1, const int* __restrict__ dst1,
    const int* __restrict__ off1, int* __restrict__ cur1,
    int* __restrict__ eidx1, const int* __restrict__ src2,
    const int* __restrict__ dst2, const int* __restrict__ off2,
    int* __restrict__ cur2, int* __restrict__ eidx2) {
  const int i = blockIdx.x * 256 + threadIdx.x;
  if (i < E1) {
    const int d = dst1[i];
    const int p = atomicAdd(&cur1[d], 1);
    eidx1[off1[d] + p] = src1[i];
  } else {
    const int j = i - E1;
    if (j < E2) {
      const int d = dst2[j];
      const int p = atomicAdd(&cur2[d], 1);
      eidx2[off2[d] + p] = src2[j];
    }
  }
}

// ---------------------------------------------------------------------------
// weight prep: Bt[n][k] bf16 (k<128: Wl1, else Wr1); B2t[n][k] bf16
// (k<256: Wl2, else Wr2)
__global__ __launch_bounds__(256) void prep_w(
    const float* __restrict__ Wl1, const float* __restrict__ Wr1,
    const float* __restrict__ Wl2, const float* __restrict__ Wr2,
    unsigned short* __restrict__ Bt, unsigned short* __restrict__ B2t) {
  const int idx = blockIdx.x * 256 + threadIdx.x;
  if (idx < 65536) {
    const int k = idx & 255, n = idx >> 8;
    const float w = (k < IN_C) ? Wl1[k * HID_C + n] : Wr1[(k - IN_C) * HID_C + n];
    Bt[n * KV + k] = (unsigned short)f2bf(w);
  } else {
    const int j = idx - 65536;  // 0..32767
    const int k = j & 511, n = j >> 9;
    const float w = (k < HID_C) ? Wl2[k * OUT_C + n] : Wr2[(k - HID_C) * OUT_C + n];
    B2t[n * KV2 + k] = (unsigned short)f2bf(w);
  }
}

// x[:N1_TGT] fp32 -> bf16 into Ab[:, 128:256]
__global__ __launch_bounds__(256) void conv_x(const float* __restrict__ x,
                                              unsigned short* __restrict__ Ab) {
  const size_t idx = (size_t)(blockIdx.x * 256 + threadIdx.x) * 4;
  const int m = (int)(idx >> 7);
  const int c = (int)(idx & 127);
  const float4 v = *reinterpret_cast<const float4*>(x + (size_t)m * IN_C + c);
  uint2 o;
  o.x = f2bf(v.x) | (f2bf(v.y) << 16);
  o.y = f2bf(v.z) | (f2bf(v.w) << 16);
  *reinterpret_cast<uint2*>(Ab + (size_t)m * KV + IN_C + c) = o;
}

// ---------------------------------------------------------------------------
// layer-1 mean-gather, bf16 out into Ab[:, 0:128]. Wave per node; half-wave
// (32 lanes x float4) covers one 512B row -> 2 edges/step, 8-edge unroll.
__global__ __launch_bounds__(256) void gather1(
    const float* __restrict__ x, const int* __restrict__ eidx,
    const int* __restrict__ off, const int* __restrict__ cnt,
    unsigned short* __restrict__ Ab) {
  const int lane = threadIdx.x & 63;
  const int half = lane >> 5;
  const int c4 = (lane & 31) * 4;
  const int node = blockIdx.x * 4 + (threadIdx.x >> 6);
  const int beg = off[node];
  const int deg = cnt[node];
  float s0 = 0, s1 = 0, s2 = 0, s3 = 0;
  float t0 = 0, t1 = 0, t2 = 0, t3 = 0;
  float u0 = 0, u1 = 0, u2 = 0, u3 = 0;
  float v0 = 0, v1 = 0, v2 = 0, v3 = 0;
  int i = 0;
  for (; i + 8 <= deg; i += 8) {
    const int n0 = eidx[beg + i + 0 + half];
    const int n1 = eidx[beg + i + 2 + half];
    const int n2 = eidx[beg + i + 4 + half];
    const int n3 = eidx[beg + i + 6 + half];
    const float4 a = *reinterpret_cast<const float4*>(x + (size_t)n0 * IN_C + c4);
    const float4 b = *reinterpret_cast<const float4*>(x + (size_t)n1 * IN_C + c4);
    const float4 c = *reinterpret_cast<const float4*>(x + (size_t)n2 * IN_C + c4);
    const float4 d = *reinterpret_cast<const float4*>(x + (size_t)n3 * IN_C + c4);
    s0 += a.x; s1 += a.y; s2 += a.z; s3 += a.w;
    t0 += b.x; t1 += b.y; t2 += b.z; t3 += b.w;
    u0 += c.x; u1 += c.y; u2 += c.z; u3 += c.w;
    v0 += d.x; v1 += d.y; v2 += d.z; v3 += d.w;
  }
  for (; i + 2 <= deg; i += 2) {
    const int n0 = eidx[beg + i + half];
    const float4 a = *reinterpret_cast<const float4*>(x + (size_t)n0 * IN_C + c4);
    s0 += a.x; s1 += a.y; s2 += a.z; s3 += a.w;
  }
  if (i < deg && half == 0) {
    const int n0 = eidx[beg + i];
    const float4 a = *reinterpret_cast<const float4*>(x + (size_t)n0 * IN_C + c4);
    s0 += a.x; s1 += a.y; s2 += a.z; s3 += a.w;
  }
  float r0 = (s0 + t0) + (u0 + v0);
  float r1 = (s1 + t1) + (u1 + v1);
  float r2 = (s2 + t2) + (u2 + v2);
  float r3 = (s3 + t3) + (u3 + v3);
  r0 += __shfl_xor(r0, 32);
  r1 += __shfl_xor(r1, 32);
  r2 += __shfl_xor(r2, 32);
  r3 += __shfl_xor(r3, 32);
  if (half == 0) {
    const float inv = 1.0f / (float)(deg > 0 ? deg : 1);
    uint2 o;
    o.x = f2bf(r0 * inv) | (f2bf(r1 * inv) << 16);
    o.y = f2bf(r2 * inv) | (f2bf(r3 * inv) << 16);
    *reinterpret_cast<uint2*>(Ab + (size_t)node * KV + c4) = o;
  }
}

// ---------------------------------------------------------------------------
// layer-1 GEMM via bf16 MFMA: h = relu(A[45056x256] @ B[256x256] + b1), bf16 out.
// Block: 64 rows x 256 cols, 4 waves each 64x64. K-step 32. (verified r4)
__global__ __launch_bounds__(256) void l1_gemm(
    const unsigned short* __restrict__ Ab, const unsigned short* __restrict__ Bt,
    const float* __restrict__ b1, unsigned short* __restrict__ h_bf) {
  __shared__ unsigned short As[64 * 40];    // padded stride 40 bf16 = 80 B
  __shared__ unsigned short Bs[256 * 40];
  const int tid = threadIdx.x;
  const int lane = tid & 63;
  const int w = tid >> 6;
  const int r0 = blockIdx.x * 64;
  const int wn = w * 64;
  f32x4 acc[4][4] = {};  // [mi][nj]
  const int arow = tid >> 2;
  const int akoff = (tid & 3) * 8;
  for (int ks = 0; ks < 8; ++ks) {
    const int k0 = ks * 32;
    if (ks) __syncthreads();
    const bf16x8 av =
        *reinterpret_cast<const bf16x8*>(Ab + (size_t)(r0 + arow) * KV + k0 + akoff);
    *reinterpret_cast<bf16x8*>(As + arow * 40 + akoff) = av;
#pragma unroll
    for (int it = 0; it < 4; ++it) {
      const int chunk = it * 256 + tid;
      const int n = chunk >> 2;
      const int koff = (chunk & 3) * 8;
      const bf16x8 bv =
          *reinterpret_cast<const bf16x8*>(Bt + (size_t)n * KV + k0 + koff);
      *reinterpret_cast<bf16x8*>(Bs + n * 40 + koff) = bv;
    }
    __syncthreads();
    const int kg = (lane >> 4) * 8;
    const int rl = lane & 15;
    bf16x8 af[4], bfr[4];
#pragma unroll
    for (int mi = 0; mi < 4; ++mi)
      af[mi] = *reinterpret_cast<const bf16x8*>(As + (mi * 16 + rl) * 40 + kg);
#pragma unroll
    for (int nj = 0; nj < 4; ++nj)
      bfr[nj] =
          *reinterpret_cast<const bf16x8*>(Bs + (wn + nj * 16 + rl) * 40 + kg);
#pragma unroll
    for (int mi = 0; mi < 4; ++mi)
#pragma unroll
      for (int nj = 0; nj < 4; ++nj)
        acc[mi][nj] = __builtin_amdgcn_mfma_f32_16x16x32_bf16(
            af[mi], bfr[nj], acc[mi][nj], 0, 0, 0);
  }
  const int rl = lane & 15;
  const int rg = lane >> 4;
#pragma unroll
  for (int nj = 0; nj < 4; ++nj) {
    const int gcol = wn + nj * 16 + rl;
    const float bias = b1[gcol];
#pragma unroll
    for (int mi = 0; mi < 4; ++mi)
#pragma unroll
      for (int r = 0; r < 4; ++r) {
        const int grow = r0 + mi * 16 + rg * 4 + r;
        const float v = fmaxf(acc[mi][nj][r] + bias, 0.0f);
        h_bf[(size_t)grow * HID_C + gcol] = (unsigned short)f2bf(v);
      }
  }
}

// ---------------------------------------------------------------------------
// layer-2 mean-gather from bf16 h -> bf16 agg2. Wave per node, 4 ch/lane.
__global__ __launch_bounds__(256) void gather2(
    const unsigned short* __restrict__ h_bf, const int* __restrict__ eidx,
    const int* __restrict__ off, const int* __restrict__ cnt,
    unsigned short* __restrict__ agg2_bf) {
  const int lane = threadIdx.x & 63;
  const int node = blockIdx.x * 4 + (threadIdx.x >> 6);
  const int beg = off[node];
  const int deg = cnt[node];
  float a0 = 0, a1 = 0, a2 = 0, a3 = 0, b0 = 0, b1v = 0, b2v = 0, b3 = 0;
  int i = 0;
  for (; i + 2 <= deg; i += 2) {
    const int n0 = eidx[beg + i], n1 = eidx[beg + i + 1];
    const uint2 ra =
        *reinterpret_cast<const uint2*>(h_bf + (size_t)n0 * HID_C + lane * 4);
    const uint2 rb =
        *reinterpret_cast<const uint2*>(h_bf + (size_t)n1 * HID_C + lane * 4);
    a0 += bf2f(ra.x & 0xffff); a1 += bf2f(ra.x >> 16);
    a2 += bf2f(ra.y & 0xffff); a3 += bf2f(ra.y >> 16);
    b0 += bf2f(rb.x & 0xffff); b1v += bf2f(rb.x >> 16);
    b2v += bf2f(rb.y & 0xffff); b3 += bf2f(rb.y >> 16);
  }
  if (i < deg) {
    const int n0 = eidx[beg + i];
    const uint2 ra =
        *reinterpret_cast<const uint2*>(h_bf + (size_t)n0 * HID_C + lane * 4);
    a0 += bf2f(ra.x & 0xffff); a1 += bf2f(ra.x >> 16);
    a2 += bf2f(ra.y & 0xffff); a3 += bf2f(ra.y >> 16);
  }
  const float inv = 1.0f / (float)(deg > 0 ? deg : 1);
  uint2 o;
  o.x = f2bf((a0 + b0) * inv) | (f2bf((a1 + b1v) * inv) << 16);
  o.y = f2bf((a2 + b2v) * inv) | (f2bf((a3 + b3) * inv) << 16);
  *reinterpret_cast<uint2*>(agg2_bf + (size_t)node * HID_C + lane * 4) = o;
}

// ---------------------------------------------------------------------------
// layer-2 GEMM (MFMA, LDS-free) + fused log-softmax.
// Block = 64 rows (4 waves x 16 rows), full N=64. K = 256 (agg2) + 256 (h).
__global__ __launch_bounds__(256) void l2_gemm_lsm(
    const unsigned short* __restrict__ agg2_bf,
    const unsigned short* __restrict__ h_bf,
    const unsigned short* __restrict__ B2t, const float* __restrict__ b2,
    float* __restrict__ out) {
  const int lane = threadIdx.x & 63;
  const int wv = threadIdx.x >> 6;
  const int r0 = blockIdx.x * 64 + wv * 16;
  const int rl = lane & 15;
  const int kg = (lane >> 4) * 8;
  f32x4 acc[4] = {};  // [nj]
#pragma unroll
  for (int phase = 0; phase < 2; ++phase) {
    const unsigned short* __restrict__ A = phase ? h_bf : agg2_bf;
#pragma unroll
    for (int ks = 0; ks < 8; ++ks) {
      const int k0 = ks * 32;
      const bf16x8 af =
          *reinterpret_cast<const bf16x8*>(A + (size_t)(r0 + rl) * HID_C + k0 + kg);
#pragma unroll
      for (int nj = 0; nj < 4; ++nj) {
        const bf16x8 bf_ = *reinterpret_cast<const bf16x8*>(
            B2t + (size_t)(nj * 16 + rl) * KV2 + phase * HID_C + k0 + kg);
        acc[nj] = __builtin_amdgcn_mfma_f32_16x16x32_bf16(af, bf_, acc[nj], 0, 0, 0);
      }
    }
  }
  const int rg = lane >> 4;  // lane holds rows rg*4+r, cols rl+nj*16
#pragma unroll
  for (int r = 0; r < 4; ++r) {
    float v[4];
#pragma unroll
    for (int nj = 0; nj < 4; ++nj) v[nj] = acc[nj][r] + b2[nj * 16 + rl];
    float m = fmaxf(fmaxf(v[0], v[1]), fmaxf(v[2], v[3]));
#pragma unroll
    for (int o = 1; o < 16; o <<= 1) m = fmaxf(m, __shfl_xor(m, o));
    float s = expf(v[0] - m) + expf(v[1] - m) + expf(v[2] - m) + expf(v[3] - m);
#pragma unroll
    for (int o = 1; o < 16; o <<= 1) s += __shfl_xor(s, o);
    const float lse = m + logf(s);
    const int grow = r0 + rg * 4 + r;
#pragma unroll
    for (int nj = 0; nj < 4; ++nj)
      out[(size_t)grow * OUT_C + nj * 16 + rl] = v[nj] - lse;
  }
}

// ---------------------------------------------------------------------------
extern "C" void kernel_launch(void* const* d_in, const int* in_sizes, int n_in,
                              void* d_out, int out_size, void* d_ws,
                              size_t ws_size, hipStream_t stream) {
  const float* x   = (const float*)d_in[0];
  const float* Wl1 = (const float*)d_in[1];
  const float* Wr1 = (const float*)d_in[2];
  const float* b1  = (const float*)d_in[3];
  const float* Wl2 = (const float*)d_in[4];
  const float* Wr2 = (const float*)d_in[5];
  const float* b2  = (const float*)d_in[6];
  const int* src1  = (const int*)d_in[7];
  const int* dst1  = (const int*)d_in[8];
  const int* src2  = (const int*)d_in[9];
  const int* dst2  = (const int*)d_in[10];

  // Workspace layout (all regions 16B-aligned)
  char* p = (char*)d_ws;
  int* cnt1 = (int*)p;                 p += (size_t)N1_TGT * 4;
  int* cur1 = (int*)p;                 p += (size_t)N1_TGT * 4;
  int* cnt2 = (int*)p;                 p += (size_t)N2_TGT * 4;
  int* cur2 = (int*)p;                 p += (size_t)N2_TGT * 4;
  const size_t zero_bytes = (size_t)(2 * N1_TGT + 2 * N2_TGT) * 4;
  int* off1 = (int*)p;                 p += (size_t)N1_TGT * 4;
  int* off2 = (int*)p;                 p += (size_t)N2_TGT * 4;
  int* part1 = (int*)p;                p += 64 * 4;
  int* part2 = (int*)p;                p += 64 * 4;
  int* eidx1 = (int*)p;                p += (size_t)E1 * 4;
  int* eidx2 = (int*)p;                p += (size_t)E2 * 4;
  unsigned short* Bt = (unsigned short*)p;      p += (size_t)HID_C * KV * 2;
  unsigned short* B2t = (unsigned short*)p;     p += (size_t)OUT_C * KV2 * 2;
  unsigned short* Ab = (unsigned short*)p;      p += (size_t)N1_TGT * KV * 2;
  unsigned short* h_bf = (unsigned short*)p;    p += (size_t)N1_TGT * HID_C * 2;
  unsigned short* agg2_bf = (unsigned short*)p; p += (size_t)N2_TGT * HID_C * 2;
  float* out = (float*)d_out;

  hipMemsetAsync(d_ws, 0, zero_bytes, stream);

  prep_w<<<dim3(384), dim3(256), 0, stream>>>(Wl1, Wr1, Wl2, Wr2, Bt, B2t);
  conv_x<<<dim3(5632), dim3(256), 0, stream>>>(x, Ab);

  // CSR build, both layers
  hist2<<<dim3(4560), dim3(256), 0, stream>>>(dst1, dst2, cnt1, cnt2);
  scan_block2<<<dim3(48), dim3(1024), 0, stream>>>(cnt1, off1, part1, cnt2,
                                                   off2, part2);
  scan_partials2<<<dim3(1), dim3(128), 0, stream>>>(part1, part2);
  scan_add2<<<dim3(192), dim3(256), 0, stream>>>(off1, part1, off2, part2);
  fill2<<<dim3(4560), dim3(256), 0, stream>>>(src1, dst1, off1, cur1, eidx1,
                                              src2, dst2, off2, cur2, eidx2);

  // layer 1
  gather1<<<dim3(N1_TGT / 4), dim3(256), 0, stream>>>(x, eidx1, off1, cnt1, Ab);
  l1_gemm<<<dim3(N1_TGT / 64), dim3(256), 0, stream>>>(Ab, Bt, b1, h_bf);

  // layer 2
  gather2<<<dim3(N2_TGT / 4), dim3(256), 0, stream>>>(h_bf, eidx2, off2, cnt2,
                                                      agg2_bf);
  l2_gemm_lsm<<<dim3(N2_TGT / 64), dim3(256), 0, stream>>>(agg2_bf, h_bf, B2t,
                                                           b2, out);
}